// Round 9
// baseline (444.291 us; speedup 1.0000x reference)
//
#include <hip/hip_runtime.h>
#include <hip/hip_bf16.h>
#include <stdint.h>

// ProjectiveAttention: out = softmax(h @ W @ h^T) @ h
// B=8, S=2048, D=800, all fp32 in/out.
// R9: co-residency restructure. R4-R8 plateaued at serial-sum cyc/K-tile
// (MFMA + ds_read + DMA, no overlap): 1 block/CU + barrier lockstep means
// pipes alternate. Fix: BM=128, BK=32, TRIPLE-buffered LDS (72KB @ 8 waves,
// 48KB @ 4-wave PV) -> 2 blocks/CU; grid 512. Cross-block async overlap
// supplies the MFMA/LDS concurrency the intra-block schedule couldn't.
// Per K32-tile: {8 ds_reads; stage t+2 (2-phase fence distance); BAR;
// 16 MFMA; VMF(S) counted, never 0 mid-loop; BAR}.

#define BB 8
#define SS 2048
#define DD 800
#define KP 832            // K padded to 26*32
#define M1 (BB*SS)        // 16384

typedef unsigned short u16;
typedef __attribute__((ext_vector_type(8))) short bf16x8;
typedef __attribute__((ext_vector_type(4))) float f32x4;

#define MFMA16(A, B, C) __builtin_amdgcn_mfma_f32_16x16x32_bf16(A, B, C, 0, 0, 0)
#define VMF(N) asm volatile("s_waitcnt vmcnt(" #N ")" ::: "memory")
#define BAR() __builtin_amdgcn_s_barrier()

__device__ __forceinline__ u16 f2bf(float x) {
    uint32_t u = __float_as_uint(x);
    uint32_t r = (u + 0x7fffu + ((u >> 16) & 1u)) >> 16;  // RTN-even
    return (u16)r;
}
__device__ __forceinline__ float bf2f(u16 h) {
    return __uint_as_float(((uint32_t)h) << 16);
}
__device__ __forceinline__ void gload16(const void* g, void* l) {
    __builtin_amdgcn_global_load_lds((__attribute__((address_space(1))) void*)g,
                                     (__attribute__((address_space(3))) void*)l,
                                     16, 0, 0);
}

// ---------------- prep kernels ----------------

// h (fp32 [16384][800]) -> h_hi/h_lo (bf16 [16384][832], k-pad zeroed)
__global__ __launch_bounds__(256) void hsplit_kernel(const float* __restrict__ x,
                                                     u16* __restrict__ hi,
                                                     u16* __restrict__ lo) {
    int idx = blockIdx.x * 256 + threadIdx.x;   // 16384*208 groups of 4 cols
    int rw = idx / 208, g = idx - rw * 208;
    ushort4 hv = {0, 0, 0, 0}, lv = {0, 0, 0, 0};
    if (g < 200) {
        float4 v = *(const float4*)(x + (long)rw * DD + g * 4);
        u16 h0 = f2bf(v.x), h1 = f2bf(v.y), h2 = f2bf(v.z), h3 = f2bf(v.w);
        hv = (ushort4){h0, h1, h2, h3};
        lv = (ushort4){f2bf(v.x - bf2f(h0)), f2bf(v.y - bf2f(h1)),
                       f2bf(v.z - bf2f(h2)), f2bf(v.w - bf2f(h3))};
    }
    *(ushort4*)(hi + (long)rw * KP + g * 4) = hv;
    *(ushort4*)(lo + (long)rw * KP + g * 4) = lv;
}

// W (fp32 [800][800]) -> Wt_hi/Wt_lo (bf16 [1024][832], transposed, pads zeroed)
__global__ __launch_bounds__(256) void wsplit_kernel(const float* __restrict__ W,
                                                     u16* __restrict__ hi,
                                                     u16* __restrict__ lo) {
    int idx = blockIdx.x * 256 + threadIdx.x;   // 1024*832
    int e = idx / KP, d = idx - e * KP;
    float v = (e < DD && d < DD) ? W[(long)d * DD + e] : 0.f;
    u16 h = f2bf(v);
    hi[idx] = h;
    lo[idx] = f2bf(v - bf2f(h));
}

// h_hi (bf16 [8][2048][832]) -> hT (bf16 [8][1024][2048], pad rows zeroed)
__global__ void transpose_kernel(const u16* __restrict__ h_hi, u16* __restrict__ hT) {
    __shared__ u16 tile[32][33];
    int b = blockIdx.z;
    int t0 = blockIdx.x * 32, d0 = blockIdx.y * 32;
    int lx = threadIdx.x, ly = threadIdx.y;
    for (int i = ly; i < 32; i += 8) {
        int d = d0 + lx;
        tile[i][lx] = (d < DD) ? h_hi[((long)b * SS + t0 + i) * KP + d] : (u16)0;
    }
    __syncthreads();
    for (int i = ly; i < 32; i += 8) {
        hT[((long)b * 1024 + d0 + i) * SS + t0 + lx] = tile[lx][i];
    }
}

// ---------------- softmax (one block per row, in-place fp32 -> bf16 attn) ------

__global__ __launch_bounds__(256) void softmax_kernel(float* __restrict__ scores) {
    const long row = blockIdx.x;
    float* p = scores + row * (long)SS;
    const int tid = threadIdx.x;
    const int lane = tid & 63, wid = tid >> 6;
    __shared__ float red[8];

    float v[8];
    float mx = -3.4e38f;
#pragma unroll
    for (int j = 0; j < 8; ++j) { v[j] = p[tid + 256 * j]; mx = fmaxf(mx, v[j]); }
#pragma unroll
    for (int o = 32; o; o >>= 1) mx = fmaxf(mx, __shfl_xor(mx, o, 64));
    if (lane == 0) red[wid] = mx;
    __syncthreads();
    mx = fmaxf(fmaxf(red[0], red[1]), fmaxf(red[2], red[3]));

    float sum = 0.f;
#pragma unroll
    for (int j = 0; j < 8; ++j) { v[j] = __expf(v[j] - mx); sum += v[j]; }
#pragma unroll
    for (int o = 32; o; o >>= 1) sum += __shfl_xor(sum, o, 64);
    if (lane == 0) red[4 + wid] = sum;
    __syncthreads();
    const float inv = 1.f / (red[4] + red[5] + red[6] + red[7]);

    u16* attn = (u16*)p;
#pragma unroll
    for (int j = 0; j < 8; ++j) attn[tid + 256 * j] = f2bf(v[j] * inv);
}

// ---------------- GEMM: C[m][n] = sum_k A[m][k]*B[n][k] ------------------------
// BM=128 x BN tile, BK=32, 2xWN waves (wave sub-tile 64x64). M batch-merged;
// when sB!=0, batch = m0>>11. SPLIT3: K'=3K via per-K32 variant
// (Ahi,Bhi)/(Ahi,Blo)/(Alo,Bhi).
//
// LDS: 3 rotating buffers; buffer = [8 A-cells | BN/16 B-cells], cell =
// [16 rows][32 k] u16 (1KB), swizzled: (r,k) at u16 r*32 + (k ^ ((r&3)<<3)).
// Stage: one gload16-wave = one cell; dest linear lane*16B; source col
// pre-XOR'd sc = ((l&3)*8) ^ (((l>>2)&3)<<3) (involution matches read).
// Read: lane l -> u16 (l&15)*32 + (((l>>4)*8) ^ ((l&3)<<3))  [R8-verified
// pattern adapted 64->32 wide; R2/R8 measured 0 conflicts].
//
// Phase (1 per K32-tile): reads(8 b128) | stage t+2 | BAR | 16 MFMA |
// VMF(SPW) counted (drains t+1, keeps t+2 in flight; never 0 mid-loop) | BAR.
// 72KB LDS (BN=256) / 48KB (BN=128) -> 2 blocks/CU: cross-block MFMA/LDS
// overlap replaces the intra-block overlap the lockstep schedule can't give.

template <int BN, int WN, int SPLIT3, int SPLIT_OUT, int NGUARD>
__global__ __launch_bounds__(128 * WN, 4) void gemmT(
    const u16* __restrict__ Ahi, const u16* __restrict__ Alo, int lda,
    const u16* __restrict__ Bhi, const u16* __restrict__ Blo, long sB, int ldb,
    float* __restrict__ C, u16* __restrict__ Chi, u16* __restrict__ Clo,
    int ldc, int Nlim, int Nbuf, int ksteps, int gmt) {
    constexpr int NCA = 8;                 // A cells (128 rows / 16)
    constexpr int NCB = BN / 16;           // B cells
    constexpr int BUFU = (NCA + NCB) * 512;
    constexpr int W = 2 * WN;              // waves
    constexpr int APW = NCA / W;           // A cells staged per wave
    constexpr int BPW = NCB / W;           // B cells staged per wave
    constexpr int SPW = APW + BPW;         // gloads per wave per stage
    extern __shared__ u16 smem[];          // [3][BUFU]

    const int tid = threadIdx.x;
    const int lane = tid & 63, wid = tid >> 6;
    const int wm = wid / WN, wn = wid % WN;

    // bijective XCD remap (m204)
    const int nwg = gridDim.x;
    const int orig = blockIdx.x;
    const int q = nwg >> 3, r = nwg & 7;
    const int xcd = orig & 7;
    const int wg = (xcd < r ? xcd * (q + 1) : r * (q + 1) + (xcd - r) * q) + (orig >> 3);
    const int m0 = (wg % gmt) * 128;
    const int n0 = (wg / gmt) * BN;

    const long boff = sB ? (long)(m0 >> 11) * sB : 0;
    const u16* Bh = Bhi + boff;
    const u16* Bl = SPLIT3 ? (Blo + boff) : nullptr;

    // staging source coords (one cell per gload16-wave)
    const int sr = lane >> 2;                                   // 0..15 row
    const int sc = ((lane & 3) * 8) ^ (((lane >> 2) & 3) << 3); // u16 col
    // fragment read offset within cell (u16)
    const int rdo = (lane & 15) * 32 + (((lane >> 4) * 8) ^ ((lane & 3) << 3));

    f32x4 acc[4][4];
#pragma unroll
    for (int i = 0; i < 4; ++i)
#pragma unroll
        for (int j = 0; j < 4; ++j) acc[i][j] = (f32x4){0.f, 0.f, 0.f, 0.f};

    auto resolve = [&](int t, const u16*& As, const u16*& Bs, int& kb) {
        if (SPLIT3) {
            int kk = t / 3, v = t - kk * 3;
            As = (v == 2) ? Alo : Ahi;
            Bs = (v == 1) ? Bl : Bh;
            kb = kk * 32;
        } else {
            As = Ahi; Bs = Bh; kb = t * 32;
        }
    };

    auto stage = [&](int t, u16* bp) {
        const u16 *As, *Bs; int kb;
        resolve(t, As, Bs, kb);
#pragma unroll
        for (int i = 0; i < APW; ++i) {
            const int c = wid * APW + i;
            gload16(As + (long)(m0 + c * 16 + sr) * lda + kb + sc,
                    bp + c * 512 + lane * 8);
        }
#pragma unroll
        for (int j = 0; j < BPW; ++j) {
            const int c = wid * BPW + j;
            gload16(Bs + (long)(n0 + c * 16 + sr) * ldb + kb + sc,
                    bp + (NCA + c) * 512 + lane * 8);
        }
    };

    // prologue: stage tiles 0,1; drain tile 0's stages (counted)
    stage(0, smem);
    if (ksteps > 1) stage(1, smem + BUFU);
    if constexpr (SPW == 3) { VMF(3); } else { VMF(4); }
    BAR();

    int bufi = 0;
    for (int t = 0; t < ksteps; ++t) {
        u16* bp = smem + bufi * BUFU;
        bf16x8 a[4], b[4];
#pragma unroll
        for (int i = 0; i < 4; ++i)
            a[i] = *(const bf16x8*)(bp + (wm * 4 + i) * 512 + rdo);
#pragma unroll
        for (int j = 0; j < 4; ++j)
            b[j] = *(const bf16x8*)(bp + (NCA + wn * 4 + j) * 512 + rdo);
        const bool h2 = (t + 2 < ksteps);
        if (h2) {
            int nb = bufi + 2; if (nb >= 3) nb -= 3;
            stage(t + 2, smem + nb * BUFU);
        }
        BAR();
        __builtin_amdgcn_s_setprio(1);
#pragma unroll
        for (int i = 0; i < 4; ++i)
#pragma unroll
            for (int j = 0; j < 4; ++j) acc[i][j] = MFMA16(a[i], b[j], acc[i][j]);
        __builtin_amdgcn_s_setprio(0);
        if (h2) {
            if constexpr (SPW == 3) { VMF(3); } else { VMF(4); }
        } else if (t + 1 < ksteps) {
            VMF(0);
        }
        BAR();
        ++bufi; if (bufi == 3) bufi = 0;
    }

    // epilogue: C/D layout col=lane&15, row=(lane>>4)*4+reg (R1-verified)
    const int rlane = lane & 15;
    const int crow = m0 + wm * 64 + (lane >> 4) * 4;
    const int ccol = n0 + wn * 64 + rlane;
#pragma unroll
    for (int i = 0; i < 4; ++i) {
#pragma unroll
        for (int j = 0; j < 4; ++j) {
            const int nn = ccol + j * 16;
            if (NGUARD && nn >= Nbuf) continue;
#pragma unroll
            for (int rr = 0; rr < 4; ++rr) {
                const int mm = crow + i * 16 + rr;
                const long off = (long)mm * ldc + nn;
                float v = acc[i][j][rr];
                if (NGUARD && nn >= Nlim) v = 0.f;
                if (SPLIT_OUT) {
                    u16 hh = f2bf(v);
                    Chi[off] = hh;
                    Clo[off] = f2bf(v - bf2f(hh));
                } else {
                    C[off] = v;
                }
            }
        }
    }
}

// ---------------- host ----------------

extern "C" void kernel_launch(void* const* d_in, const int* in_sizes, int n_in,
                              void* d_out, int out_size, void* d_ws, size_t ws_size,
                              hipStream_t stream) {
    const float* h = (const float*)d_in[0];
    const float* W = (const float*)d_in[1];
    float* out = (float*)d_out;

    char* ws = (char*)d_ws;
    size_t off = 0;
    auto alloc = [&](size_t bytes) -> void* {
        void* p = ws + off;
        off += (bytes + 255) & ~(size_t)255;
        return p;
    };
    const size_t MD = (size_t)M1 * KP;
    u16* h_hi  = (u16*)alloc(MD * 2);
    u16* h_lo  = (u16*)alloc(MD * 2);
    u16* hW_hi = (u16*)alloc(MD * 2);
    u16* hW_lo = (u16*)alloc(MD * 2);
    u16* hT    = (u16*)alloc((size_t)BB * 1024 * SS * 2);
    u16* Wt_hi = (u16*)alloc((size_t)1024 * KP * 2);
    u16* Wt_lo = (u16*)alloc((size_t)1024 * KP * 2);
    float* scores = (float*)alloc((size_t)4 * SS * SS * 4);   // 4-batch chunk

    hipFuncSetAttribute(reinterpret_cast<const void*>(&gemmT<256, 4, 1, 1, 1>),
                        hipFuncAttributeMaxDynamicSharedMemorySize, 73728);
    hipFuncSetAttribute(reinterpret_cast<const void*>(&gemmT<256, 4, 1, 0, 0>),
                        hipFuncAttributeMaxDynamicSharedMemorySize, 73728);
    hipFuncSetAttribute(reinterpret_cast<const void*>(&gemmT<128, 2, 0, 0, 1>),
                        hipFuncAttributeMaxDynamicSharedMemorySize, 49152);

    // prep
    hsplit_kernel<<<dim3(16384 * 208 / 256), dim3(256), 0, stream>>>(h, h_hi, h_lo);
    wsplit_kernel<<<dim3(1024 * KP / 256), dim3(256), 0, stream>>>(W, Wt_hi, Wt_lo);
    transpose_kernel<<<dim3(SS / 32, 32, BB), dim3(32, 8), 0, stream>>>(h_hi, hT);

    // GEMM1: hW = h @ W  (M=16384, N=1024pad, K'=78 K32-tiles), split-out
    gemmT<256, 4, 1, 1, 1><<<dim3(512), dim3(512), 73728, stream>>>(
        h_hi, h_lo, KP,
        Wt_hi, Wt_lo, 0L, KP,
        nullptr, hW_hi, hW_lo,
        KP, DD, KP, 78, 128);

    for (int b0 = 0; b0 < BB; b0 += 4) {
        const long aoff = (long)b0 * SS * KP;
        // GEMM2: scores = hW @ h^T  (chunk M=8192 m-merged, N=2048/batch, K'=78)
        gemmT<256, 4, 1, 0, 0><<<dim3(512), dim3(512), 73728, stream>>>(
            hW_hi + aoff, hW_lo + aoff, KP,
            h_hi + aoff, h_lo + aoff, (long)SS * KP, KP,
            scores, nullptr, nullptr,
            SS, SS, SS, 78, 64);
        // softmax rows -> bf16 attn in place (pitch 4096 u16)
        softmax_kernel<<<dim3(4 * SS), dim3(256), 0, stream>>>(scores);
        // PV: out = attn @ h  (chunk M=8192, N=1024pad/BN128, K=2048)
        gemmT<128, 2, 0, 0, 1><<<dim3(512), dim3(256), 49152, stream>>>(
            (const u16*)scores, nullptr, SS * 2,
            hT + (long)b0 * 1024 * SS, nullptr, (long)1024 * SS, SS,
            out + (long)b0 * SS * DD, nullptr, nullptr,
            DD, DD, DD, 64, 64);
    }
}

// Round 10
// 436.773 us; speedup vs baseline: 1.0172x; 1.0172x over previous
//
#include <hip/hip_runtime.h>
#include <hip/hip_bf16.h>
#include <stdint.h>

// ProjectiveAttention: out = softmax(h @ W @ h^T) @ h
// B=8, S=2048, D=800, all fp32 in/out.
// R9: co-residency (BM=128, BK=32, triple-buffer, 2 blocks/CU).
// R10: fix the 32-wide-cell swizzle. R9 folded row bits 0-1 into the k-slot;
// a 32-k row is 4 slots wide so bank = (r&1)*64 + ((kq^(r&3))*16) -> lanes
// r,r+4 collide (2-way, 1.02e7 conflicts). Correct fold = row bits 1-2:
// (r,k) at r*32 + (k ^ (((r>>1)&3)<<3)); stage sc and read rdo updated as the
// same involution. Enumerated: each 8-lane group -> 8 distinct 16B slots.
// Also: PV grid 8->7 N-tiles (896 >= 800), -12.5% PV work.

#define BB 8
#define SS 2048
#define DD 800
#define KP 832            // K padded to 26*32
#define M1 (BB*SS)        // 16384

typedef unsigned short u16;
typedef __attribute__((ext_vector_type(8))) short bf16x8;
typedef __attribute__((ext_vector_type(4))) float f32x4;

#define MFMA16(A, B, C) __builtin_amdgcn_mfma_f32_16x16x32_bf16(A, B, C, 0, 0, 0)
#define VMF(N) asm volatile("s_waitcnt vmcnt(" #N ")" ::: "memory")
#define BAR() __builtin_amdgcn_s_barrier()

__device__ __forceinline__ u16 f2bf(float x) {
    uint32_t u = __float_as_uint(x);
    uint32_t r = (u + 0x7fffu + ((u >> 16) & 1u)) >> 16;  // RTN-even
    return (u16)r;
}
__device__ __forceinline__ float bf2f(u16 h) {
    return __uint_as_float(((uint32_t)h) << 16);
}
__device__ __forceinline__ void gload16(const void* g, void* l) {
    __builtin_amdgcn_global_load_lds((__attribute__((address_space(1))) void*)g,
                                     (__attribute__((address_space(3))) void*)l,
                                     16, 0, 0);
}

// ---------------- prep kernels ----------------

// h (fp32 [16384][800]) -> h_hi/h_lo (bf16 [16384][832], k-pad zeroed)
__global__ __launch_bounds__(256) void hsplit_kernel(const float* __restrict__ x,
                                                     u16* __restrict__ hi,
                                                     u16* __restrict__ lo) {
    int idx = blockIdx.x * 256 + threadIdx.x;   // 16384*208 groups of 4 cols
    int rw = idx / 208, g = idx - rw * 208;
    ushort4 hv = {0, 0, 0, 0}, lv = {0, 0, 0, 0};
    if (g < 200) {
        float4 v = *(const float4*)(x + (long)rw * DD + g * 4);
        u16 h0 = f2bf(v.x), h1 = f2bf(v.y), h2 = f2bf(v.z), h3 = f2bf(v.w);
        hv = (ushort4){h0, h1, h2, h3};
        lv = (ushort4){f2bf(v.x - bf2f(h0)), f2bf(v.y - bf2f(h1)),
                       f2bf(v.z - bf2f(h2)), f2bf(v.w - bf2f(h3))};
    }
    *(ushort4*)(hi + (long)rw * KP + g * 4) = hv;
    *(ushort4*)(lo + (long)rw * KP + g * 4) = lv;
}

// W (fp32 [800][800]) -> Wt_hi/Wt_lo (bf16 [1024][832], transposed, pads zeroed)
__global__ __launch_bounds__(256) void wsplit_kernel(const float* __restrict__ W,
                                                     u16* __restrict__ hi,
                                                     u16* __restrict__ lo) {
    int idx = blockIdx.x * 256 + threadIdx.x;   // 1024*832
    int e = idx / KP, d = idx - e * KP;
    float v = (e < DD && d < DD) ? W[(long)d * DD + e] : 0.f;
    u16 h = f2bf(v);
    hi[idx] = h;
    lo[idx] = f2bf(v - bf2f(h));
}

// h_hi (bf16 [8][2048][832]) -> hT (bf16 [8][1024][2048], pad rows zeroed)
__global__ void transpose_kernel(const u16* __restrict__ h_hi, u16* __restrict__ hT) {
    __shared__ u16 tile[32][33];
    int b = blockIdx.z;
    int t0 = blockIdx.x * 32, d0 = blockIdx.y * 32;
    int lx = threadIdx.x, ly = threadIdx.y;
    for (int i = ly; i < 32; i += 8) {
        int d = d0 + lx;
        tile[i][lx] = (d < DD) ? h_hi[((long)b * SS + t0 + i) * KP + d] : (u16)0;
    }
    __syncthreads();
    for (int i = ly; i < 32; i += 8) {
        hT[((long)b * 1024 + d0 + i) * SS + t0 + lx] = tile[lx][i];
    }
}

// ---------------- softmax (one block per row, in-place fp32 -> bf16 attn) ------

__global__ __launch_bounds__(256) void softmax_kernel(float* __restrict__ scores) {
    const long row = blockIdx.x;
    float* p = scores + row * (long)SS;
    const int tid = threadIdx.x;
    const int lane = tid & 63, wid = tid >> 6;
    __shared__ float red[8];

    float v[8];
    float mx = -3.4e38f;
#pragma unroll
    for (int j = 0; j < 8; ++j) { v[j] = p[tid + 256 * j]; mx = fmaxf(mx, v[j]); }
#pragma unroll
    for (int o = 32; o; o >>= 1) mx = fmaxf(mx, __shfl_xor(mx, o, 64));
    if (lane == 0) red[wid] = mx;
    __syncthreads();
    mx = fmaxf(fmaxf(red[0], red[1]), fmaxf(red[2], red[3]));

    float sum = 0.f;
#pragma unroll
    for (int j = 0; j < 8; ++j) { v[j] = __expf(v[j] - mx); sum += v[j]; }
#pragma unroll
    for (int o = 32; o; o >>= 1) sum += __shfl_xor(sum, o, 64);
    if (lane == 0) red[4 + wid] = sum;
    __syncthreads();
    const float inv = 1.f / (red[4] + red[5] + red[6] + red[7]);

    u16* attn = (u16*)p;
#pragma unroll
    for (int j = 0; j < 8; ++j) attn[tid + 256 * j] = f2bf(v[j] * inv);
}

// ---------------- GEMM: C[m][n] = sum_k A[m][k]*B[n][k] ------------------------
// BM=128 x BN tile, BK=32, 2xWN waves (wave sub-tile 64x64). M batch-merged;
// when sB!=0, batch = m0>>11. SPLIT3: K'=3K via per-K32 variant
// (Ahi,Bhi)/(Ahi,Blo)/(Alo,Bhi).
//
// LDS: 3 rotating buffers; buffer = [8 A-cells | BN/16 B-cells], cell =
// [16 rows][32 k] u16 (1KB), swizzled: (r,k) at u16 r*32 + (k ^ (((r>>1)&3)<<3)).
// Stage: one gload16-wave = one cell; dest linear lane*16B; source col
// pre-XOR'd sc = ((l&3)*8) ^ (((l>>3)&3)<<3)  [row = l>>2 -> row bits 1-2].
// Read: lane l -> u16 (l&15)*32 + (((l>>4)*8) ^ (((l>>1)&3)<<3)).
// Bank check (enumerated): every consecutive 8-lane group covers 8 distinct
// 16B slots mod 128B -> conflict-free reads; DMA writes linear.
//
// Phase (1 per K32-tile): reads(8 b128) | stage t+2 | BAR | 16 MFMA |
// VMF(SPW) counted (drains t+1, keeps t+2 in flight; never 0 mid-loop) | BAR.
// 72KB LDS (BN=256) / 48KB (BN=128) -> 2 blocks/CU for cross-block overlap.

template <int BN, int WN, int SPLIT3, int SPLIT_OUT, int NGUARD>
__global__ __launch_bounds__(128 * WN, 4) void gemmT(
    const u16* __restrict__ Ahi, const u16* __restrict__ Alo, int lda,
    const u16* __restrict__ Bhi, const u16* __restrict__ Blo, long sB, int ldb,
    float* __restrict__ C, u16* __restrict__ Chi, u16* __restrict__ Clo,
    int ldc, int Nlim, int Nbuf, int ksteps, int gmt) {
    constexpr int NCA = 8;                 // A cells (128 rows / 16)
    constexpr int NCB = BN / 16;           // B cells
    constexpr int BUFU = (NCA + NCB) * 512;
    constexpr int W = 2 * WN;              // waves
    constexpr int APW = NCA / W;           // A cells staged per wave
    constexpr int BPW = NCB / W;           // B cells staged per wave
    constexpr int SPW = APW + BPW;         // gloads per wave per stage
    extern __shared__ u16 smem[];          // [3][BUFU]

    const int tid = threadIdx.x;
    const int lane = tid & 63, wid = tid >> 6;
    const int wm = wid / WN, wn = wid % WN;

    // bijective XCD remap (m204)
    const int nwg = gridDim.x;
    const int orig = blockIdx.x;
    const int q = nwg >> 3, r = nwg & 7;
    const int xcd = orig & 7;
    const int wg = (xcd < r ? xcd * (q + 1) : r * (q + 1) + (xcd - r) * q) + (orig >> 3);
    const int m0 = (wg % gmt) * 128;
    const int n0 = (wg / gmt) * BN;

    const long boff = sB ? (long)(m0 >> 11) * sB : 0;
    const u16* Bh = Bhi + boff;
    const u16* Bl = SPLIT3 ? (Blo + boff) : nullptr;

    // staging source coords (one cell per gload16-wave); row = l>>2
    const int sr = lane >> 2;                                   // 0..15 row
    const int sc = ((lane & 3) * 8) ^ (((lane >> 3) & 3) << 3); // u16 col (R10 fix)
    // fragment read offset within cell (u16): row = l&15, kq = l>>4
    const int rdo = (lane & 15) * 32 + (((lane >> 4) * 8) ^ (((lane >> 1) & 3) << 3));

    f32x4 acc[4][4];
#pragma unroll
    for (int i = 0; i < 4; ++i)
#pragma unroll
        for (int j = 0; j < 4; ++j) acc[i][j] = (f32x4){0.f, 0.f, 0.f, 0.f};

    auto resolve = [&](int t, const u16*& As, const u16*& Bs, int& kb) {
        if (SPLIT3) {
            int kk = t / 3, v = t - kk * 3;
            As = (v == 2) ? Alo : Ahi;
            Bs = (v == 1) ? Bl : Bh;
            kb = kk * 32;
        } else {
            As = Ahi; Bs = Bh; kb = t * 32;
        }
    };

    auto stage = [&](int t, u16* bp) {
        const u16 *As, *Bs; int kb;
        resolve(t, As, Bs, kb);
#pragma unroll
        for (int i = 0; i < APW; ++i) {
            const int c = wid * APW + i;
            gload16(As + (long)(m0 + c * 16 + sr) * lda + kb + sc,
                    bp + c * 512 + lane * 8);
        }
#pragma unroll
        for (int j = 0; j < BPW; ++j) {
            const int c = wid * BPW + j;
            gload16(Bs + (long)(n0 + c * 16 + sr) * ldb + kb + sc,
                    bp + (NCA + c) * 512 + lane * 8);
        }
    };

    // prologue: stage tiles 0,1; drain tile 0's stages (counted)
    stage(0, smem);
    if (ksteps > 1) stage(1, smem + BUFU);
    if constexpr (SPW == 3) { VMF(3); } else { VMF(4); }
    BAR();

    int bufi = 0;
    for (int t = 0; t < ksteps; ++t) {
        u16* bp = smem + bufi * BUFU;
        bf16x8 a[4], b[4];
#pragma unroll
        for (int i = 0; i < 4; ++i)
            a[i] = *(const bf16x8*)(bp + (wm * 4 + i) * 512 + rdo);
#pragma unroll
        for (int j = 0; j < 4; ++j)
            b[j] = *(const bf16x8*)(bp + (NCA + wn * 4 + j) * 512 + rdo);
        const bool h2 = (t + 2 < ksteps);
        if (h2) {
            int nb = bufi + 2; if (nb >= 3) nb -= 3;
            stage(t + 2, smem + nb * BUFU);
        }
        BAR();
        __builtin_amdgcn_s_setprio(1);
#pragma unroll
        for (int i = 0; i < 4; ++i)
#pragma unroll
            for (int j = 0; j < 4; ++j) acc[i][j] = MFMA16(a[i], b[j], acc[i][j]);
        __builtin_amdgcn_s_setprio(0);
        if (h2) {
            if constexpr (SPW == 3) { VMF(3); } else { VMF(4); }
        } else if (t + 1 < ksteps) {
            VMF(0);
        }
        BAR();
        ++bufi; if (bufi == 3) bufi = 0;
    }

    // epilogue: C/D layout col=lane&15, row=(lane>>4)*4+reg (R1-verified)
    const int rlane = lane & 15;
    const int crow = m0 + wm * 64 + (lane >> 4) * 4;
    const int ccol = n0 + wn * 64 + rlane;
#pragma unroll
    for (int i = 0; i < 4; ++i) {
#pragma unroll
        for (int j = 0; j < 4; ++j) {
            const int nn = ccol + j * 16;
            if (NGUARD && nn >= Nbuf) continue;
#pragma unroll
            for (int rr = 0; rr < 4; ++rr) {
                const int mm = crow + i * 16 + rr;
                const long off = (long)mm * ldc + nn;
                float v = acc[i][j][rr];
                if (NGUARD && nn >= Nlim) v = 0.f;
                if (SPLIT_OUT) {
                    u16 hh = f2bf(v);
                    Chi[off] = hh;
                    Clo[off] = f2bf(v - bf2f(hh));
                } else {
                    C[off] = v;
                }
            }
        }
    }
}

// ---------------- host ----------------

extern "C" void kernel_launch(void* const* d_in, const int* in_sizes, int n_in,
                              void* d_out, int out_size, void* d_ws, size_t ws_size,
                              hipStream_t stream) {
    const float* h = (const float*)d_in[0];
    const float* W = (const float*)d_in[1];
    float* out = (float*)d_out;

    char* ws = (char*)d_ws;
    size_t off = 0;
    auto alloc = [&](size_t bytes) -> void* {
        void* p = ws + off;
        off += (bytes + 255) & ~(size_t)255;
        return p;
    };
    const size_t MD = (size_t)M1 * KP;
    u16* h_hi  = (u16*)alloc(MD * 2);
    u16* h_lo  = (u16*)alloc(MD * 2);
    u16* hW_hi = (u16*)alloc(MD * 2);
    u16* hW_lo = (u16*)alloc(MD * 2);
    u16* hT    = (u16*)alloc((size_t)BB * 1024 * SS * 2);
    u16* Wt_hi = (u16*)alloc((size_t)1024 * KP * 2);
    u16* Wt_lo = (u16*)alloc((size_t)1024 * KP * 2);
    float* scores = (float*)alloc((size_t)4 * SS * SS * 4);   // 4-batch chunk

    hipFuncSetAttribute(reinterpret_cast<const void*>(&gemmT<256, 4, 1, 1, 1>),
                        hipFuncAttributeMaxDynamicSharedMemorySize, 73728);
    hipFuncSetAttribute(reinterpret_cast<const void*>(&gemmT<256, 4, 1, 0, 0>),
                        hipFuncAttributeMaxDynamicSharedMemorySize, 73728);
    hipFuncSetAttribute(reinterpret_cast<const void*>(&gemmT<128, 2, 0, 0, 1>),
                        hipFuncAttributeMaxDynamicSharedMemorySize, 49152);

    // prep
    hsplit_kernel<<<dim3(16384 * 208 / 256), dim3(256), 0, stream>>>(h, h_hi, h_lo);
    wsplit_kernel<<<dim3(1024 * KP / 256), dim3(256), 0, stream>>>(W, Wt_hi, Wt_lo);
    transpose_kernel<<<dim3(SS / 32, 32, BB), dim3(32, 8), 0, stream>>>(h_hi, hT);

    // GEMM1: hW = h @ W  (M=16384, N=1024pad, K'=78 K32-tiles), split-out
    gemmT<256, 4, 1, 1, 1><<<dim3(512), dim3(512), 73728, stream>>>(
        h_hi, h_lo, KP,
        Wt_hi, Wt_lo, 0L, KP,
        nullptr, hW_hi, hW_lo,
        KP, DD, KP, 78, 128);

    for (int b0 = 0; b0 < BB; b0 += 4) {
        const long aoff = (long)b0 * SS * KP;
        // GEMM2: scores = hW @ h^T  (chunk M=8192 m-merged, N=2048/batch, K'=78)
        gemmT<256, 4, 1, 0, 0><<<dim3(512), dim3(512), 73728, stream>>>(
            hW_hi + aoff, hW_lo + aoff, KP,
            h_hi + aoff, h_lo + aoff, (long)SS * KP, KP,
            scores, nullptr, nullptr,
            SS, SS, SS, 78, 64);
        // softmax rows -> bf16 attn in place (pitch 4096 u16)
        softmax_kernel<<<dim3(4 * SS), dim3(256), 0, stream>>>(scores);
        // PV: out = attn @ h  (chunk M=8192, N=7x128=896>=800, K=2048)
        gemmT<128, 2, 0, 0, 1><<<dim3(448), dim3(256), 49152, stream>>>(
            (const u16*)scores, nullptr, SS * 2,
            hT + (long)b0 * 1024 * SS, nullptr, (long)1024 * SS, SS,
            out + (long)b0 * SS * DD, nullptr, nullptr,
            DD, DD, DD, 64, 64);
    }
}

// Round 12
// 426.468 us; speedup vs baseline: 1.0418x; 1.0242x over previous
//
#include <hip/hip_runtime.h>
#include <hip/hip_bf16.h>
#include <stdint.h>

// ProjectiveAttention: out = softmax(h @ W @ h^T) @ h
// B=8, S=2048, D=800, all fp32 in/out.
// R10: co-residency + conflict-free 32-wide swizzle (verified: conflicts=0).
// R11/R12: FUSED-variant split3. Previously each variant (hh/hl/lh) was its
// own K-tile: Ahi staged+read 2x, Bhi 2x per K32. Measured budget: LDS-read
// BW is the wall (2304 cyc reads vs 466 MFMA per K32/CU). Fusion: stage
// {Ahi,Alo,Bhi,Blo} once per K32 (48 cells), read 16 b128/wave -> 48 MFMA
// (reads/MFMA 0.5 -> 0.33; DMA -33%). Triple-buffer 144KB, stage-2-ahead +
// counted fence (literal via if constexpr - R11 died on macro stringify).

#define BB 8
#define SS 2048
#define DD 800
#define KP 832            // K padded to 26*32
#define M1 (BB*SS)        // 16384

typedef unsigned short u16;
typedef __attribute__((ext_vector_type(8))) short bf16x8;
typedef __attribute__((ext_vector_type(4))) float f32x4;

#define MFMA16(A, B, C) __builtin_amdgcn_mfma_f32_16x16x32_bf16(A, B, C, 0, 0, 0)
#define VMF(N) asm volatile("s_waitcnt vmcnt(" #N ")" ::: "memory")
#define BAR() __builtin_amdgcn_s_barrier()

template <int SPW>
__device__ __forceinline__ void vmf_spw() {
    static_assert(SPW == 3 || SPW == 4 || SPW == 6, "unsupported SPW");
    if constexpr (SPW == 6) { VMF(6); }
    else if constexpr (SPW == 4) { VMF(4); }
    else { VMF(3); }
}

__device__ __forceinline__ u16 f2bf(float x) {
    uint32_t u = __float_as_uint(x);
    uint32_t r = (u + 0x7fffu + ((u >> 16) & 1u)) >> 16;  // RTN-even
    return (u16)r;
}
__device__ __forceinline__ float bf2f(u16 h) {
    return __uint_as_float(((uint32_t)h) << 16);
}
__device__ __forceinline__ void gload16(const void* g, void* l) {
    __builtin_amdgcn_global_load_lds((__attribute__((address_space(1))) void*)g,
                                     (__attribute__((address_space(3))) void*)l,
                                     16, 0, 0);
}

// ---------------- prep kernels ----------------

// h (fp32 [16384][800]) -> h_hi/h_lo (bf16 [16384][832], k-pad zeroed)
__global__ __launch_bounds__(256) void hsplit_kernel(const float* __restrict__ x,
                                                     u16* __restrict__ hi,
                                                     u16* __restrict__ lo) {
    int idx = blockIdx.x * 256 + threadIdx.x;   // 16384*208 groups of 4 cols
    int rw = idx / 208, g = idx - rw * 208;
    ushort4 hv = {0, 0, 0, 0}, lv = {0, 0, 0, 0};
    if (g < 200) {
        float4 v = *(const float4*)(x + (long)rw * DD + g * 4);
        u16 h0 = f2bf(v.x), h1 = f2bf(v.y), h2 = f2bf(v.z), h3 = f2bf(v.w);
        hv = (ushort4){h0, h1, h2, h3};
        lv = (ushort4){f2bf(v.x - bf2f(h0)), f2bf(v.y - bf2f(h1)),
                       f2bf(v.z - bf2f(h2)), f2bf(v.w - bf2f(h3))};
    }
    *(ushort4*)(hi + (long)rw * KP + g * 4) = hv;
    *(ushort4*)(lo + (long)rw * KP + g * 4) = lv;
}

// W (fp32 [800][800]) -> Wt_hi/Wt_lo (bf16 [1024][832], transposed, pads zeroed)
__global__ __launch_bounds__(256) void wsplit_kernel(const float* __restrict__ W,
                                                     u16* __restrict__ hi,
                                                     u16* __restrict__ lo) {
    int idx = blockIdx.x * 256 + threadIdx.x;   // 1024*832
    int e = idx / KP, d = idx - e * KP;
    float v = (e < DD && d < DD) ? W[(long)d * DD + e] : 0.f;
    u16 h = f2bf(v);
    hi[idx] = h;
    lo[idx] = f2bf(v - bf2f(h));
}

// h_hi (bf16 [8][2048][832]) -> hT (bf16 [8][1024][2048], pad rows zeroed)
__global__ void transpose_kernel(const u16* __restrict__ h_hi, u16* __restrict__ hT) {
    __shared__ u16 tile[32][33];
    int b = blockIdx.z;
    int t0 = blockIdx.x * 32, d0 = blockIdx.y * 32;
    int lx = threadIdx.x, ly = threadIdx.y;
    for (int i = ly; i < 32; i += 8) {
        int d = d0 + lx;
        tile[i][lx] = (d < DD) ? h_hi[((long)b * SS + t0 + i) * KP + d] : (u16)0;
    }
    __syncthreads();
    for (int i = ly; i < 32; i += 8) {
        hT[((long)b * 1024 + d0 + i) * SS + t0 + lx] = tile[lx][i];
    }
}

// ---------------- softmax (one block per row, in-place fp32 -> bf16 attn) ------

__global__ __launch_bounds__(256) void softmax_kernel(float* __restrict__ scores) {
    const long row = blockIdx.x;
    float* p = scores + row * (long)SS;
    const int tid = threadIdx.x;
    const int lane = tid & 63, wid = tid >> 6;
    __shared__ float red[8];

    float v[8];
    float mx = -3.4e38f;
#pragma unroll
    for (int j = 0; j < 8; ++j) { v[j] = p[tid + 256 * j]; mx = fmaxf(mx, v[j]); }
#pragma unroll
    for (int o = 32; o; o >>= 1) mx = fmaxf(mx, __shfl_xor(mx, o, 64));
    if (lane == 0) red[wid] = mx;
    __syncthreads();
    mx = fmaxf(fmaxf(red[0], red[1]), fmaxf(red[2], red[3]));

    float sum = 0.f;
#pragma unroll
    for (int j = 0; j < 8; ++j) { v[j] = __expf(v[j] - mx); sum += v[j]; }
#pragma unroll
    for (int o = 32; o; o >>= 1) sum += __shfl_xor(sum, o, 64);
    if (lane == 0) red[4 + wid] = sum;
    __syncthreads();
    const float inv = 1.f / (red[4] + red[5] + red[6] + red[7]);

    u16* attn = (u16*)p;
#pragma unroll
    for (int j = 0; j < 8; ++j) attn[tid + 256 * j] = f2bf(v[j] * inv);
}

// ---------------- GEMM: C[m][n] = sum_k A[m][k]*B[n][k] ------------------------
// BM=128 x BN tile, BK=32, 2xWN waves (wave sub-tile 64x64). M batch-merged;
// when sB!=0, batch = m0>>11.
//
// LDS cell = [16 rows][32 k] u16 (1KB), swizzle (r,k) -> r*32 + (k^(((r>>1)&3)<<3));
// stage source col pre-XOR'd sc = ((l&3)*8) ^ (((l>>3)&3)<<3), dest linear
// lane*16B; read rdo = (l&15)*32 + (((l>>4)*8) ^ (((l>>1)&3)<<3)).
// [R10-verified: SQ_LDS_BANK_CONFLICT = 0.]
//
// SPLIT3 (fused): buffer = [Ahi 8][Alo 8][Bhi 16][Blo 16] cells (48KB);
// per wave per K32: 16 b128 reads -> 48 MFMA (hh+hl+lh per acc). Stage map
// per wave: 1 Ahi + 1 Alo + 2 Bhi + 2 Blo = 6 gloads (static). Triple-buffer
// (144KB), stage t+2 ahead, counted fence VMF(6) - never 0 mid-loop.
// Non-split (PV): buffer = [A 8][B NCB] cells, as R10.

template <int BN, int WN, int SPLIT3, int SPLIT_OUT, int NGUARD>
__global__ __launch_bounds__(128 * WN, SPLIT3 ? 2 : 4) void gemmT(
    const u16* __restrict__ Ahi, const u16* __restrict__ Alo, int lda,
    const u16* __restrict__ Bhi, const u16* __restrict__ Blo, long sB, int ldb,
    float* __restrict__ C, u16* __restrict__ Chi, u16* __restrict__ Clo,
    int ldc, int Nlim, int Nbuf, int ksteps, int gmt) {
    constexpr int NCA = 8;                 // A cells (128 rows / 16)
    constexpr int NCB = BN / 16;           // B cells
    constexpr int BUFU = SPLIT3 ? (2 * NCA + 2 * NCB) * 512 : (NCA + NCB) * 512;
    constexpr int W = 2 * WN;              // waves
    constexpr int SPW = SPLIT3 ? 6 : ((NCA + NCB) / W);  // gloads/wave/stage
    extern __shared__ u16 smem[];          // [3][BUFU]

    const int tid = threadIdx.x;
    const int lane = tid & 63, wid = tid >> 6;
    const int wm = wid / WN, wn = wid % WN;

    // bijective XCD remap (m204)
    const int nwg = gridDim.x;
    const int orig = blockIdx.x;
    const int q = nwg >> 3, r = nwg & 7;
    const int xcd = orig & 7;
    const int wg = (xcd < r ? xcd * (q + 1) : r * (q + 1) + (xcd - r) * q) + (orig >> 3);
    const int m0 = (wg % gmt) * 128;
    const int n0 = (wg / gmt) * BN;

    const long boff = sB ? (long)(m0 >> 11) * sB : 0;
    const u16* Bh = Bhi + boff;
    const u16* Bl = SPLIT3 ? (Blo + boff) : nullptr;

    // staging source coords (one cell per gload16-wave); row = l>>2
    const int sr = lane >> 2;                                   // 0..15 row
    const int sc = ((lane & 3) * 8) ^ (((lane >> 3) & 3) << 3); // u16 col
    // fragment read offset within cell (u16): row = l&15, kq = l>>4
    const int rdo = (lane & 15) * 32 + (((lane >> 4) * 8) ^ (((lane >> 1) & 3) << 3));

    f32x4 acc[4][4];
#pragma unroll
    for (int i = 0; i < 4; ++i)
#pragma unroll
        for (int j = 0; j < 4; ++j) acc[i][j] = (f32x4){0.f, 0.f, 0.f, 0.f};

    // ---- staging ----
    auto stage = [&](int t, u16* bp) {
        const int kb = t * 32;
        if constexpr (SPLIT3) {
            // A: cell wid (hi), 8+wid (lo)
            gload16(Ahi + (long)(m0 + wid * 16 + sr) * lda + kb + sc,
                    bp + wid * 512 + lane * 8);
            gload16(Alo + (long)(m0 + wid * 16 + sr) * lda + kb + sc,
                    bp + (NCA + wid) * 512 + lane * 8);
            // B: cells 2wid, 2wid+1 (hi then lo)
#pragma unroll
            for (int j = 0; j < 2; ++j) {
                const int c = 2 * wid + j;
                gload16(Bh + (long)(n0 + c * 16 + sr) * ldb + kb + sc,
                        bp + (2 * NCA + c) * 512 + lane * 8);
                gload16(Bl + (long)(n0 + c * 16 + sr) * ldb + kb + sc,
                        bp + (2 * NCA + NCB + c) * 512 + lane * 8);
            }
        } else {
            constexpr int APW = NCA / W, BPW = NCB / W;
#pragma unroll
            for (int i = 0; i < APW; ++i) {
                const int c = wid * APW + i;
                gload16(Ahi + (long)(m0 + c * 16 + sr) * lda + kb + sc,
                        bp + c * 512 + lane * 8);
            }
#pragma unroll
            for (int j = 0; j < BPW; ++j) {
                const int c = wid * BPW + j;
                gload16(Bh + (long)(n0 + c * 16 + sr) * ldb + kb + sc,
                        bp + (NCA + c) * 512 + lane * 8);
            }
        }
    };

    // prologue: stage tiles 0,1; drain tile 0's stages (counted)
    stage(0, smem);
    if (ksteps > 1) stage(1, smem + BUFU);
    vmf_spw<SPW>();
    BAR();

    int bufi = 0;
    for (int t = 0; t < ksteps; ++t) {
        u16* bp = smem + bufi * BUFU;
        const bool h2 = (t + 2 < ksteps);
        if constexpr (SPLIT3) {
            bf16x8 ah[4], al[4], bh[4], bl[4];
#pragma unroll
            for (int i = 0; i < 4; ++i) {
                ah[i] = *(const bf16x8*)(bp + (wm * 4 + i) * 512 + rdo);
                al[i] = *(const bf16x8*)(bp + (NCA + wm * 4 + i) * 512 + rdo);
            }
#pragma unroll
            for (int j = 0; j < 4; ++j) {
                bh[j] = *(const bf16x8*)(bp + (2 * NCA + wn * 4 + j) * 512 + rdo);
                bl[j] = *(const bf16x8*)(bp + (2 * NCA + NCB + wn * 4 + j) * 512 + rdo);
            }
            if (h2) {
                int nb = bufi + 2; if (nb >= 3) nb -= 3;
                stage(t + 2, smem + nb * BUFU);
            }
            BAR();
            __builtin_amdgcn_s_setprio(1);
#pragma unroll
            for (int i = 0; i < 4; ++i)
#pragma unroll
                for (int j = 0; j < 4; ++j) {
                    acc[i][j] = MFMA16(ah[i], bh[j], acc[i][j]);
                    acc[i][j] = MFMA16(ah[i], bl[j], acc[i][j]);
                    acc[i][j] = MFMA16(al[i], bh[j], acc[i][j]);
                }
            __builtin_amdgcn_s_setprio(0);
        } else {
            bf16x8 a[4], b[4];
#pragma unroll
            for (int i = 0; i < 4; ++i)
                a[i] = *(const bf16x8*)(bp + (wm * 4 + i) * 512 + rdo);
#pragma unroll
            for (int j = 0; j < 4; ++j)
                b[j] = *(const bf16x8*)(bp + (NCA + wn * 4 + j) * 512 + rdo);
            if (h2) {
                int nb = bufi + 2; if (nb >= 3) nb -= 3;
                stage(t + 2, smem + nb * BUFU);
            }
            BAR();
            __builtin_amdgcn_s_setprio(1);
#pragma unroll
            for (int i = 0; i < 4; ++i)
#pragma unroll
                for (int j = 0; j < 4; ++j) acc[i][j] = MFMA16(a[i], b[j], acc[i][j]);
            __builtin_amdgcn_s_setprio(0);
        }
        if (h2) {
            vmf_spw<SPW>();
        } else if (t + 1 < ksteps) {
            VMF(0);
        }
        BAR();
        ++bufi; if (bufi == 3) bufi = 0;
    }

    // epilogue: C/D layout col=lane&15, row=(lane>>4)*4+reg (R1-verified)
    const int rlane = lane & 15;
    const int crow = m0 + wm * 64 + (lane >> 4) * 4;
    const int ccol = n0 + wn * 64 + rlane;
#pragma unroll
    for (int i = 0; i < 4; ++i) {
#pragma unroll
        for (int j = 0; j < 4; ++j) {
            const int nn = ccol + j * 16;
            if (NGUARD && nn >= Nbuf) continue;
#pragma unroll
            for (int rr = 0; rr < 4; ++rr) {
                const int mm = crow + i * 16 + rr;
                const long off = (long)mm * ldc + nn;
                float v = acc[i][j][rr];
                if (NGUARD && nn >= Nlim) v = 0.f;
                if (SPLIT_OUT) {
                    u16 hh = f2bf(v);
                    Chi[off] = hh;
                    Clo[off] = f2bf(v - bf2f(hh));
                } else {
                    C[off] = v;
                }
            }
        }
    }
}

// ---------------- host ----------------

extern "C" void kernel_launch(void* const* d_in, const int* in_sizes, int n_in,
                              void* d_out, int out_size, void* d_ws, size_t ws_size,
                              hipStream_t stream) {
    const float* h = (const float*)d_in[0];
    const float* W = (const float*)d_in[1];
    float* out = (float*)d_out;

    char* ws = (char*)d_ws;
    size_t off = 0;
    auto alloc = [&](size_t bytes) -> void* {
        void* p = ws + off;
        off += (bytes + 255) & ~(size_t)255;
        return p;
    };
    const size_t MD = (size_t)M1 * KP;
    u16* h_hi  = (u16*)alloc(MD * 2);
    u16* h_lo  = (u16*)alloc(MD * 2);
    u16* hW_hi = (u16*)alloc(MD * 2);
    u16* hW_lo = (u16*)alloc(MD * 2);
    u16* hT    = (u16*)alloc((size_t)BB * 1024 * SS * 2);
    u16* Wt_hi = (u16*)alloc((size_t)1024 * KP * 2);
    u16* Wt_lo = (u16*)alloc((size_t)1024 * KP * 2);
    float* scores = (float*)alloc((size_t)4 * SS * SS * 4);   // 4-batch chunk

    (void)hipFuncSetAttribute(reinterpret_cast<const void*>(&gemmT<256, 4, 1, 1, 1>),
                              hipFuncAttributeMaxDynamicSharedMemorySize, 147456);
    (void)hipFuncSetAttribute(reinterpret_cast<const void*>(&gemmT<256, 4, 1, 0, 0>),
                              hipFuncAttributeMaxDynamicSharedMemorySize, 147456);
    (void)hipFuncSetAttribute(reinterpret_cast<const void*>(&gemmT<128, 2, 0, 0, 1>),
                              hipFuncAttributeMaxDynamicSharedMemorySize, 49152);

    // prep
    hsplit_kernel<<<dim3(16384 * 208 / 256), dim3(256), 0, stream>>>(h, h_hi, h_lo);
    wsplit_kernel<<<dim3(1024 * KP / 256), dim3(256), 0, stream>>>(W, Wt_hi, Wt_lo);
    transpose_kernel<<<dim3(SS / 32, 32, BB), dim3(32, 8), 0, stream>>>(h_hi, hT);

    // GEMM1: hW = h @ W  (M=16384, N=1024pad, 26 K32-tiles fused), split-out
    gemmT<256, 4, 1, 1, 1><<<dim3(512), dim3(512), 147456, stream>>>(
        h_hi, h_lo, KP,
        Wt_hi, Wt_lo, 0L, KP,
        nullptr, hW_hi, hW_lo,
        KP, DD, KP, 26, 128);

    for (int b0 = 0; b0 < BB; b0 += 4) {
        const long aoff = (long)b0 * SS * KP;
        // GEMM2: scores = hW @ h^T  (chunk M=8192 m-merged, N=2048/batch, 26 K32)
        gemmT<256, 4, 1, 0, 0><<<dim3(512), dim3(512), 147456, stream>>>(
            hW_hi + aoff, hW_lo + aoff, KP,
            h_hi + aoff, h_lo + aoff, (long)SS * KP, KP,
            scores, nullptr, nullptr,
            SS, SS, SS, 26, 64);
        // softmax rows -> bf16 attn in place (pitch 4096 u16)
        softmax_kernel<<<dim3(4 * SS), dim3(256), 0, stream>>>(scores);
        // PV: out = attn @ h  (chunk M=8192, N=7x128=896>=800, K=2048)
        gemmT<128, 2, 0, 0, 1><<<dim3(448), dim3(256), 49152, stream>>>(
            (const u16*)scores, nullptr, SS * 2,
            hT + (long)b0 * 1024 * SS, nullptr, (long)1024 * SS, SS,
            out + (long)b0 * SS * DD, nullptr, nullptr,
            DD, DD, DD, 64, 64);
    }
}

// Round 13
// 415.221 us; speedup vs baseline: 1.0700x; 1.0271x over previous
//
#include <hip/hip_runtime.h>
#include <hip/hip_bf16.h>
#include <stdint.h>

// ProjectiveAttention: out = softmax(h @ W @ h^T) @ h
// B=8, S=2048, D=800, all fp32 in/out.
// R10: conflict-free 32-wide swizzle (verified 0 conflicts).
// R12: fused-variant split3 (stage {Ahi,Alo,Bhi,Blo} once/K32, 16 reads ->
//      48 MFMA). Null vs R10 => LDS-read-BW model refuted; stall is barrier
//      lockstep (measured 4615 cyc/K32 vs 2400 serial-sum).
// R13: SINGLE barrier per K32. Triple-buffer + stage-2-ahead makes the
// mid-loop BAR redundant: VMF(SPW)@end of t-1 drains stage(t) (12->6
// outstanding), BAR publishes; overwrite target buf[(t-1)%3]'s readers
// finished before their MFMA(t-1) (lgkmcnt) hence before the BAR. 26 sync
// points instead of 52; waves may skew within an iteration (reads of one
// wave overlap MFMA of another on the same SIMD). Stage issued at top (T14).

#define BB 8
#define SS 2048
#define DD 800
#define KP 832            // K padded to 26*32
#define M1 (BB*SS)        // 16384

typedef unsigned short u16;
typedef __attribute__((ext_vector_type(8))) short bf16x8;
typedef __attribute__((ext_vector_type(4))) float f32x4;

#define MFMA16(A, B, C) __builtin_amdgcn_mfma_f32_16x16x32_bf16(A, B, C, 0, 0, 0)
#define VMF(N) asm volatile("s_waitcnt vmcnt(" #N ")" ::: "memory")
#define BAR() __builtin_amdgcn_s_barrier()

template <int SPW>
__device__ __forceinline__ void vmf_spw() {
    static_assert(SPW == 3 || SPW == 4 || SPW == 6, "unsupported SPW");
    if constexpr (SPW == 6) { VMF(6); }
    else if constexpr (SPW == 4) { VMF(4); }
    else { VMF(3); }
}

__device__ __forceinline__ u16 f2bf(float x) {
    uint32_t u = __float_as_uint(x);
    uint32_t r = (u + 0x7fffu + ((u >> 16) & 1u)) >> 16;  // RTN-even
    return (u16)r;
}
__device__ __forceinline__ float bf2f(u16 h) {
    return __uint_as_float(((uint32_t)h) << 16);
}
__device__ __forceinline__ void gload16(const void* g, void* l) {
    __builtin_amdgcn_global_load_lds((__attribute__((address_space(1))) void*)g,
                                     (__attribute__((address_space(3))) void*)l,
                                     16, 0, 0);
}

// ---------------- prep kernels ----------------

// h (fp32 [16384][800]) -> h_hi/h_lo (bf16 [16384][832], k-pad zeroed)
__global__ __launch_bounds__(256) void hsplit_kernel(const float* __restrict__ x,
                                                     u16* __restrict__ hi,
                                                     u16* __restrict__ lo) {
    int idx = blockIdx.x * 256 + threadIdx.x;   // 16384*208 groups of 4 cols
    int rw = idx / 208, g = idx - rw * 208;
    ushort4 hv = {0, 0, 0, 0}, lv = {0, 0, 0, 0};
    if (g < 200) {
        float4 v = *(const float4*)(x + (long)rw * DD + g * 4);
        u16 h0 = f2bf(v.x), h1 = f2bf(v.y), h2 = f2bf(v.z), h3 = f2bf(v.w);
        hv = (ushort4){h0, h1, h2, h3};
        lv = (ushort4){f2bf(v.x - bf2f(h0)), f2bf(v.y - bf2f(h1)),
                       f2bf(v.z - bf2f(h2)), f2bf(v.w - bf2f(h3))};
    }
    *(ushort4*)(hi + (long)rw * KP + g * 4) = hv;
    *(ushort4*)(lo + (long)rw * KP + g * 4) = lv;
}

// W (fp32 [800][800]) -> Wt_hi/Wt_lo (bf16 [1024][832], transposed, pads zeroed)
__global__ __launch_bounds__(256) void wsplit_kernel(const float* __restrict__ W,
                                                     u16* __restrict__ hi,
                                                     u16* __restrict__ lo) {
    int idx = blockIdx.x * 256 + threadIdx.x;   // 1024*832
    int e = idx / KP, d = idx - e * KP;
    float v = (e < DD && d < DD) ? W[(long)d * DD + e] : 0.f;
    u16 h = f2bf(v);
    hi[idx] = h;
    lo[idx] = f2bf(v - bf2f(h));
}

// h_hi (bf16 [8][2048][832]) -> hT (bf16 [8][1024][2048], pad rows zeroed)
__global__ void transpose_kernel(const u16* __restrict__ h_hi, u16* __restrict__ hT) {
    __shared__ u16 tile[32][33];
    int b = blockIdx.z;
    int t0 = blockIdx.x * 32, d0 = blockIdx.y * 32;
    int lx = threadIdx.x, ly = threadIdx.y;
    for (int i = ly; i < 32; i += 8) {
        int d = d0 + lx;
        tile[i][lx] = (d < DD) ? h_hi[((long)b * SS + t0 + i) * KP + d] : (u16)0;
    }
    __syncthreads();
    for (int i = ly; i < 32; i += 8) {
        hT[((long)b * 1024 + d0 + i) * SS + t0 + lx] = tile[lx][i];
    }
}

// ---------------- softmax (one block per row, in-place fp32 -> bf16 attn) ------

__global__ __launch_bounds__(256) void softmax_kernel(float* __restrict__ scores) {
    const long row = blockIdx.x;
    float* p = scores + row * (long)SS;
    const int tid = threadIdx.x;
    const int lane = tid & 63, wid = tid >> 6;
    __shared__ float red[8];

    float v[8];
    float mx = -3.4e38f;
#pragma unroll
    for (int j = 0; j < 8; ++j) { v[j] = p[tid + 256 * j]; mx = fmaxf(mx, v[j]); }
#pragma unroll
    for (int o = 32; o; o >>= 1) mx = fmaxf(mx, __shfl_xor(mx, o, 64));
    if (lane == 0) red[wid] = mx;
    __syncthreads();
    mx = fmaxf(fmaxf(red[0], red[1]), fmaxf(red[2], red[3]));

    float sum = 0.f;
#pragma unroll
    for (int j = 0; j < 8; ++j) { v[j] = __expf(v[j] - mx); sum += v[j]; }
#pragma unroll
    for (int o = 32; o; o >>= 1) sum += __shfl_xor(sum, o, 64);
    if (lane == 0) red[4 + wid] = sum;
    __syncthreads();
    const float inv = 1.f / (red[4] + red[5] + red[6] + red[7]);

    u16* attn = (u16*)p;
#pragma unroll
    for (int j = 0; j < 8; ++j) attn[tid + 256 * j] = f2bf(v[j] * inv);
}

// ---------------- GEMM: C[m][n] = sum_k A[m][k]*B[n][k] ------------------------
// BM=128 x BN tile, BK=32, 2xWN waves (wave sub-tile 64x64). M batch-merged;
// when sB!=0, batch = m0>>11.
//
// LDS cell = [16 rows][32 k] u16 (1KB), swizzle (r,k) -> r*32 + (k^(((r>>1)&3)<<3));
// stage source col pre-XOR'd sc = ((l&3)*8) ^ (((l>>3)&3)<<3), dest linear
// lane*16B; read rdo = (l&15)*32 + (((l>>4)*8) ^ (((l>>1)&3)<<3)).
// [R10-verified: SQ_LDS_BANK_CONFLICT = 0.]
//
// SPLIT3 (fused): buffer = [Ahi 8][Alo 8][Bhi 16][Blo 16] cells (48KB);
// 16 b128 reads/wave -> 48 MFMA. Triple-buffer, stage t+2 ahead.
// K32 iteration (ONE barrier): stage(t+2); reads(t); MFMA; VMF(SPW); BAR.
// Safety: VMF@t-1 drains stage(t) (12->6 outstanding), BAR publishes;
// overwrite target's readers finished before their MFMA(t-1) hence the BAR.

template <int BN, int WN, int SPLIT3, int SPLIT_OUT, int NGUARD>
__global__ __launch_bounds__(128 * WN, SPLIT3 ? 2 : 4) void gemmT(
    const u16* __restrict__ Ahi, const u16* __restrict__ Alo, int lda,
    const u16* __restrict__ Bhi, const u16* __restrict__ Blo, long sB, int ldb,
    float* __restrict__ C, u16* __restrict__ Chi, u16* __restrict__ Clo,
    int ldc, int Nlim, int Nbuf, int ksteps, int gmt) {
    constexpr int NCA = 8;                 // A cells (128 rows / 16)
    constexpr int NCB = BN / 16;           // B cells
    constexpr int BUFU = SPLIT3 ? (2 * NCA + 2 * NCB) * 512 : (NCA + NCB) * 512;
    constexpr int W = 2 * WN;              // waves
    constexpr int SPW = SPLIT3 ? 6 : ((NCA + NCB) / W);  // gloads/wave/stage
    extern __shared__ u16 smem[];          // [3][BUFU]

    const int tid = threadIdx.x;
    const int lane = tid & 63, wid = tid >> 6;
    const int wm = wid / WN, wn = wid % WN;

    // bijective XCD remap (m204)
    const int nwg = gridDim.x;
    const int orig = blockIdx.x;
    const int q = nwg >> 3, r = nwg & 7;
    const int xcd = orig & 7;
    const int wg = (xcd < r ? xcd * (q + 1) : r * (q + 1) + (xcd - r) * q) + (orig >> 3);
    const int m0 = (wg % gmt) * 128;
    const int n0 = (wg / gmt) * BN;

    const long boff = sB ? (long)(m0 >> 11) * sB : 0;
    const u16* Bh = Bhi + boff;
    const u16* Bl = SPLIT3 ? (Blo + boff) : nullptr;

    // staging source coords (one cell per gload16-wave); row = l>>2
    const int sr = lane >> 2;                                   // 0..15 row
    const int sc = ((lane & 3) * 8) ^ (((lane >> 3) & 3) << 3); // u16 col
    // fragment read offset within cell (u16): row = l&15, kq = l>>4
    const int rdo = (lane & 15) * 32 + (((lane >> 4) * 8) ^ (((lane >> 1) & 3) << 3));

    f32x4 acc[4][4];
#pragma unroll
    for (int i = 0; i < 4; ++i)
#pragma unroll
        for (int j = 0; j < 4; ++j) acc[i][j] = (f32x4){0.f, 0.f, 0.f, 0.f};

    // ---- staging ----
    auto stage = [&](int t, u16* bp) {
        const int kb = t * 32;
        if constexpr (SPLIT3) {
            // A: cell wid (hi), 8+wid (lo)
            gload16(Ahi + (long)(m0 + wid * 16 + sr) * lda + kb + sc,
                    bp + wid * 512 + lane * 8);
            gload16(Alo + (long)(m0 + wid * 16 + sr) * lda + kb + sc,
                    bp + (NCA + wid) * 512 + lane * 8);
            // B: cells 2wid, 2wid+1 (hi then lo)
#pragma unroll
            for (int j = 0; j < 2; ++j) {
                const int c = 2 * wid + j;
                gload16(Bh + (long)(n0 + c * 16 + sr) * ldb + kb + sc,
                        bp + (2 * NCA + c) * 512 + lane * 8);
                gload16(Bl + (long)(n0 + c * 16 + sr) * ldb + kb + sc,
                        bp + (2 * NCA + NCB + c) * 512 + lane * 8);
            }
        } else {
            constexpr int APW = NCA / W, BPW = NCB / W;
#pragma unroll
            for (int i = 0; i < APW; ++i) {
                const int c = wid * APW + i;
                gload16(Ahi + (long)(m0 + c * 16 + sr) * lda + kb + sc,
                        bp + c * 512 + lane * 8);
            }
#pragma unroll
            for (int j = 0; j < BPW; ++j) {
                const int c = wid * BPW + j;
                gload16(Bh + (long)(n0 + c * 16 + sr) * ldb + kb + sc,
                        bp + (NCA + c) * 512 + lane * 8);
            }
        }
    };

    // prologue: stage tiles 0,1; drain tile 0's stages (counted)
    stage(0, smem);
    if (ksteps > 1) stage(1, smem + BUFU);
    vmf_spw<SPW>();
    BAR();

    int bufi = 0;
    for (int t = 0; t < ksteps; ++t) {
        u16* bp = smem + bufi * BUFU;
        const bool h2 = (t + 2 < ksteps);
        // issue next-next tile's DMA first (T14 issue-early; disjoint buffer)
        if (h2) {
            int nb = bufi + 2; if (nb >= 3) nb -= 3;
            stage(t + 2, smem + nb * BUFU);
        }
        if constexpr (SPLIT3) {
            bf16x8 ah[4], al[4], bh[4], bl[4];
#pragma unroll
            for (int i = 0; i < 4; ++i) {
                ah[i] = *(const bf16x8*)(bp + (wm * 4 + i) * 512 + rdo);
                al[i] = *(const bf16x8*)(bp + (NCA + wm * 4 + i) * 512 + rdo);
            }
#pragma unroll
            for (int j = 0; j < 4; ++j) {
                bh[j] = *(const bf16x8*)(bp + (2 * NCA + wn * 4 + j) * 512 + rdo);
                bl[j] = *(const bf16x8*)(bp + (2 * NCA + NCB + wn * 4 + j) * 512 + rdo);
            }
            __builtin_amdgcn_s_setprio(1);
#pragma unroll
            for (int i = 0; i < 4; ++i)
#pragma unroll
                for (int j = 0; j < 4; ++j) {
                    acc[i][j] = MFMA16(ah[i], bh[j], acc[i][j]);
                    acc[i][j] = MFMA16(ah[i], bl[j], acc[i][j]);
                    acc[i][j] = MFMA16(al[i], bh[j], acc[i][j]);
                }
            __builtin_amdgcn_s_setprio(0);
        } else {
            bf16x8 a[4], b[4];
#pragma unroll
            for (int i = 0; i < 4; ++i)
                a[i] = *(const bf16x8*)(bp + (wm * 4 + i) * 512 + rdo);
#pragma unroll
            for (int j = 0; j < 4; ++j)
                b[j] = *(const bf16x8*)(bp + (NCA + wn * 4 + j) * 512 + rdo);
            __builtin_amdgcn_s_setprio(1);
#pragma unroll
            for (int i = 0; i < 4; ++i)
#pragma unroll
                for (int j = 0; j < 4; ++j) acc[i][j] = MFMA16(a[i], b[j], acc[i][j]);
            __builtin_amdgcn_s_setprio(0);
        }
        // single per-iteration fence+barrier: drains stage(t+1), publishes
        if (h2) {
            vmf_spw<SPW>();
        } else if (t + 1 < ksteps) {
            VMF(0);
        }
        BAR();
        ++bufi; if (bufi == 3) bufi = 0;
    }

    // epilogue: C/D layout col=lane&15, row=(lane>>4)*4+reg (R1-verified)
    const int rlane = lane & 15;
    const int crow = m0 + wm * 64 + (lane >> 4) * 4;
    const int ccol = n0 + wn * 64 + rlane;
#pragma unroll
    for (int i = 0; i < 4; ++i) {
#pragma unroll
        for (int j = 0; j < 4; ++j) {
            const int nn = ccol + j * 16;
            if (NGUARD && nn >= Nbuf) continue;
#pragma unroll
            for (int rr = 0; rr < 4; ++rr) {
                const int mm = crow + i * 16 + rr;
                const long off = (long)mm * ldc + nn;
                float v = acc[i][j][rr];
                if (NGUARD && nn >= Nlim) v = 0.f;
                if (SPLIT_OUT) {
                    u16 hh = f2bf(v);
                    Chi[off] = hh;
                    Clo[off] = f2bf(v - bf2f(hh));
                } else {
                    C[off] = v;
                }
            }
        }
    }
}

// ---------------- host ----------------

extern "C" void kernel_launch(void* const* d_in, const int* in_sizes, int n_in,
                              void* d_out, int out_size, void* d_ws, size_t ws_size,
                              hipStream_t stream) {
    const float* h = (const float*)d_in[0];
    const float* W = (const float*)d_in[1];
    float* out = (float*)d_out;

    char* ws = (char*)d_ws;
    size_t off = 0;
    auto alloc = [&](size_t bytes) -> void* {
        void* p = ws + off;
        off += (bytes + 255) & ~(size_t)255;
        return p;
    };
    const size_t MD = (size_t)M1 * KP;
    u16* h_hi  = (u16*)alloc(MD * 2);
    u16* h_lo  = (u16*)alloc(MD * 2);
    u16* hW_hi = (u16*)alloc(MD * 2);
    u16* hW_lo = (u16*)alloc(MD * 2);
    u16* hT    = (u16*)alloc((size_t)BB * 1024 * SS * 2);
    u16* Wt_hi = (u16*)alloc((size_t)1024 * KP * 2);
    u16* Wt_lo = (u16*)alloc((size_t)1024 * KP * 2);
    float* scores = (float*)alloc((size_t)4 * SS * SS * 4);   // 4-batch chunk

    (void)hipFuncSetAttribute(reinterpret_cast<const void*>(&gemmT<256, 4, 1, 1, 1>),
                              hipFuncAttributeMaxDynamicSharedMemorySize, 147456);
    (void)hipFuncSetAttribute(reinterpret_cast<const void*>(&gemmT<256, 4, 1, 0, 0>),
                              hipFuncAttributeMaxDynamicSharedMemorySize, 147456);
    (void)hipFuncSetAttribute(reinterpret_cast<const void*>(&gemmT<128, 2, 0, 0, 1>),
                              hipFuncAttributeMaxDynamicSharedMemorySize, 49152);

    // prep
    hsplit_kernel<<<dim3(16384 * 208 / 256), dim3(256), 0, stream>>>(h, h_hi, h_lo);
    wsplit_kernel<<<dim3(1024 * KP / 256), dim3(256), 0, stream>>>(W, Wt_hi, Wt_lo);
    transpose_kernel<<<dim3(SS / 32, 32, BB), dim3(32, 8), 0, stream>>>(h_hi, hT);

    // GEMM1: hW = h @ W  (M=16384, N=1024pad, 26 K32-tiles fused), split-out
    gemmT<256, 4, 1, 1, 1><<<dim3(512), dim3(512), 147456, stream>>>(
        h_hi, h_lo, KP,
        Wt_hi, Wt_lo, 0L, KP,
        nullptr, hW_hi, hW_lo,
        KP, DD, KP, 26, 128);

    for (int b0 = 0; b0 < BB; b0 += 4) {
        const long aoff = (long)b0 * SS * KP;
        // GEMM2: scores = hW @ h^T  (chunk M=8192 m-merged, N=2048/batch, 26 K32)
        gemmT<256, 4, 1, 0, 0><<<dim3(512), dim3(512), 147456, stream>>>(
            hW_hi + aoff, hW_lo + aoff, KP,
            h_hi + aoff, h_lo + aoff, (long)SS * KP, KP,
            scores, nullptr, nullptr,
            SS, SS, SS, 26, 64);
        // softmax rows -> bf16 attn in place (pitch 4096 u16)
        softmax_kernel<<<dim3(4 * SS), dim3(256), 0, stream>>>(scores);
        // PV: out = attn @ h  (chunk M=8192, N=7x128=896>=800, K=2048)
        gemmT<128, 2, 0, 0, 1><<<dim3(448), dim3(256), 49152, stream>>>(
            (const u16*)scores, nullptr, SS * 2,
            hT + (long)b0 * 1024 * SS, nullptr, (long)1024 * SS, SS,
            out + (long)b0 * SS * DD, nullptr, nullptr,
            DD, DD, DD, 64, 64);
    }
}

// Round 14
// 411.969 us; speedup vs baseline: 1.0785x; 1.0079x over previous
//
#include <hip/hip_runtime.h>
#include <hip/hip_bf16.h>
#include <stdint.h>

// ProjectiveAttention: out = softmax(h @ W @ h^T) @ h
// B=8, S=2048, D=800, all fp32 in/out.
// R10: conflict-free 32-wide swizzle (verified 0 conflicts).
// R12: fused-variant split3 (stage once/K32, 16 reads -> 48 MFMA).
// R13: single barrier per K32 (+8% GEMM).
// R14: break the accumulator dependency chain. R12/R13 issued the 3 variant
// products back-to-back into the SAME acc[i][j] -> each MFMA stalls at
// latency (~17cyc) not throughput (4.85); with 2 waves/SIMD nothing hides
// it (this is why R12's read-savings were null: 3x R10's per-iter time).
// Fix: variant-outermost order - 15 independent MFMAs between acc reuses.
// Per-element accumulation order unchanged (hh->hl->lh): bit-identical.

#define BB 8
#define SS 2048
#define DD 800
#define KP 832            // K padded to 26*32
#define M1 (BB*SS)        // 16384

typedef unsigned short u16;
typedef __attribute__((ext_vector_type(8))) short bf16x8;
typedef __attribute__((ext_vector_type(4))) float f32x4;

#define MFMA16(A, B, C) __builtin_amdgcn_mfma_f32_16x16x32_bf16(A, B, C, 0, 0, 0)
#define VMF(N) asm volatile("s_waitcnt vmcnt(" #N ")" ::: "memory")
#define BAR() __builtin_amdgcn_s_barrier()

template <int SPW>
__device__ __forceinline__ void vmf_spw() {
    static_assert(SPW == 3 || SPW == 4 || SPW == 6, "unsupported SPW");
    if constexpr (SPW == 6) { VMF(6); }
    else if constexpr (SPW == 4) { VMF(4); }
    else { VMF(3); }
}

__device__ __forceinline__ u16 f2bf(float x) {
    uint32_t u = __float_as_uint(x);
    uint32_t r = (u + 0x7fffu + ((u >> 16) & 1u)) >> 16;  // RTN-even
    return (u16)r;
}
__device__ __forceinline__ float bf2f(u16 h) {
    return __uint_as_float(((uint32_t)h) << 16);
}
__device__ __forceinline__ void gload16(const void* g, void* l) {
    __builtin_amdgcn_global_load_lds((__attribute__((address_space(1))) void*)g,
                                     (__attribute__((address_space(3))) void*)l,
                                     16, 0, 0);
}

// ---------------- prep kernels ----------------

// h (fp32 [16384][800]) -> h_hi/h_lo (bf16 [16384][832], k-pad zeroed)
__global__ __launch_bounds__(256) void hsplit_kernel(const float* __restrict__ x,
                                                     u16* __restrict__ hi,
                                                     u16* __restrict__ lo) {
    int idx = blockIdx.x * 256 + threadIdx.x;   // 16384*208 groups of 4 cols
    int rw = idx / 208, g = idx - rw * 208;
    ushort4 hv = {0, 0, 0, 0}, lv = {0, 0, 0, 0};
    if (g < 200) {
        float4 v = *(const float4*)(x + (long)rw * DD + g * 4);
        u16 h0 = f2bf(v.x), h1 = f2bf(v.y), h2 = f2bf(v.z), h3 = f2bf(v.w);
        hv = (ushort4){h0, h1, h2, h3};
        lv = (ushort4){f2bf(v.x - bf2f(h0)), f2bf(v.y - bf2f(h1)),
                       f2bf(v.z - bf2f(h2)), f2bf(v.w - bf2f(h3))};
    }
    *(ushort4*)(hi + (long)rw * KP + g * 4) = hv;
    *(ushort4*)(lo + (long)rw * KP + g * 4) = lv;
}

// W (fp32 [800][800]) -> Wt_hi/Wt_lo (bf16 [1024][832], transposed, pads zeroed)
__global__ __launch_bounds__(256) void wsplit_kernel(const float* __restrict__ W,
                                                     u16* __restrict__ hi,
                                                     u16* __restrict__ lo) {
    int idx = blockIdx.x * 256 + threadIdx.x;   // 1024*832
    int e = idx / KP, d = idx - e * KP;
    float v = (e < DD && d < DD) ? W[(long)d * DD + e] : 0.f;
    u16 h = f2bf(v);
    hi[idx] = h;
    lo[idx] = f2bf(v - bf2f(h));
}

// h_hi (bf16 [8][2048][832]) -> hT (bf16 [8][1024][2048], pad rows zeroed)
__global__ void transpose_kernel(const u16* __restrict__ h_hi, u16* __restrict__ hT) {
    __shared__ u16 tile[32][33];
    int b = blockIdx.z;
    int t0 = blockIdx.x * 32, d0 = blockIdx.y * 32;
    int lx = threadIdx.x, ly = threadIdx.y;
    for (int i = ly; i < 32; i += 8) {
        int d = d0 + lx;
        tile[i][lx] = (d < DD) ? h_hi[((long)b * SS + t0 + i) * KP + d] : (u16)0;
    }
    __syncthreads();
    for (int i = ly; i < 32; i += 8) {
        hT[((long)b * 1024 + d0 + i) * SS + t0 + lx] = tile[lx][i];
    }
}

// ---------------- softmax (one block per row, in-place fp32 -> bf16 attn) ------

__global__ __launch_bounds__(256) void softmax_kernel(float* __restrict__ scores) {
    const long row = blockIdx.x;
    float* p = scores + row * (long)SS;
    const int tid = threadIdx.x;
    const int lane = tid & 63, wid = tid >> 6;
    __shared__ float red[8];

    float v[8];
    float mx = -3.4e38f;
#pragma unroll
    for (int j = 0; j < 8; ++j) { v[j] = p[tid + 256 * j]; mx = fmaxf(mx, v[j]); }
#pragma unroll
    for (int o = 32; o; o >>= 1) mx = fmaxf(mx, __shfl_xor(mx, o, 64));
    if (lane == 0) red[wid] = mx;
    __syncthreads();
    mx = fmaxf(fmaxf(red[0], red[1]), fmaxf(red[2], red[3]));

    float sum = 0.f;
#pragma unroll
    for (int j = 0; j < 8; ++j) { v[j] = __expf(v[j] - mx); sum += v[j]; }
#pragma unroll
    for (int o = 32; o; o >>= 1) sum += __shfl_xor(sum, o, 64);
    if (lane == 0) red[4 + wid] = sum;
    __syncthreads();
    const float inv = 1.f / (red[4] + red[5] + red[6] + red[7]);

    u16* attn = (u16*)p;
#pragma unroll
    for (int j = 0; j < 8; ++j) attn[tid + 256 * j] = f2bf(v[j] * inv);
}

// ---------------- GEMM: C[m][n] = sum_k A[m][k]*B[n][k] ------------------------
// BM=128 x BN tile, BK=32, 2xWN waves (wave sub-tile 64x64). M batch-merged;
// when sB!=0, batch = m0>>11.
//
// LDS cell = [16 rows][32 k] u16 (1KB), swizzle (r,k) -> r*32 + (k^(((r>>1)&3)<<3));
// stage source col pre-XOR'd sc = ((l&3)*8) ^ (((l>>3)&3)<<3), dest linear
// lane*16B; read rdo = (l&15)*32 + (((l>>4)*8) ^ (((l>>1)&3)<<3)).
// [R10-verified: SQ_LDS_BANK_CONFLICT = 0.]
//
// SPLIT3 (fused): buffer = [Ahi 8][Alo 8][Bhi 16][Blo 16] cells (48KB);
// 16 b128 reads/wave -> 48 MFMA, variant-outermost (no acc dep chains).
// Triple-buffer, stage t+2 ahead, ONE barrier per K32 (R13-verified safe).

template <int BN, int WN, int SPLIT3, int SPLIT_OUT, int NGUARD>
__global__ __launch_bounds__(128 * WN, SPLIT3 ? 2 : 4) void gemmT(
    const u16* __restrict__ Ahi, const u16* __restrict__ Alo, int lda,
    const u16* __restrict__ Bhi, const u16* __restrict__ Blo, long sB, int ldb,
    float* __restrict__ C, u16* __restrict__ Chi, u16* __restrict__ Clo,
    int ldc, int Nlim, int Nbuf, int ksteps, int gmt) {
    constexpr int NCA = 8;                 // A cells (128 rows / 16)
    constexpr int NCB = BN / 16;           // B cells
    constexpr int BUFU = SPLIT3 ? (2 * NCA + 2 * NCB) * 512 : (NCA + NCB) * 512;
    constexpr int W = 2 * WN;              // waves
    constexpr int SPW = SPLIT3 ? 6 : ((NCA + NCB) / W);  // gloads/wave/stage
    extern __shared__ u16 smem[];          // [3][BUFU]

    const int tid = threadIdx.x;
    const int lane = tid & 63, wid = tid >> 6;
    const int wm = wid / WN, wn = wid % WN;

    // bijective XCD remap (m204)
    const int nwg = gridDim.x;
    const int orig = blockIdx.x;
    const int q = nwg >> 3, r = nwg & 7;
    const int xcd = orig & 7;
    const int wg = (xcd < r ? xcd * (q + 1) : r * (q + 1) + (xcd - r) * q) + (orig >> 3);
    const int m0 = (wg % gmt) * 128;
    const int n0 = (wg / gmt) * BN;

    const long boff = sB ? (long)(m0 >> 11) * sB : 0;
    const u16* Bh = Bhi + boff;
    const u16* Bl = SPLIT3 ? (Blo + boff) : nullptr;

    // staging source coords (one cell per gload16-wave); row = l>>2
    const int sr = lane >> 2;                                   // 0..15 row
    const int sc = ((lane & 3) * 8) ^ (((lane >> 3) & 3) << 3); // u16 col
    // fragment read offset within cell (u16): row = l&15, kq = l>>4
    const int rdo = (lane & 15) * 32 + (((lane >> 4) * 8) ^ (((lane >> 1) & 3) << 3));

    f32x4 acc[4][4];
#pragma unroll
    for (int i = 0; i < 4; ++i)
#pragma unroll
        for (int j = 0; j < 4; ++j) acc[i][j] = (f32x4){0.f, 0.f, 0.f, 0.f};

    // ---- staging ----
    auto stage = [&](int t, u16* bp) {
        const int kb = t * 32;
        if constexpr (SPLIT3) {
            // A: cell wid (hi), 8+wid (lo)
            gload16(Ahi + (long)(m0 + wid * 16 + sr) * lda + kb + sc,
                    bp + wid * 512 + lane * 8);
            gload16(Alo + (long)(m0 + wid * 16 + sr) * lda + kb + sc,
                    bp + (NCA + wid) * 512 + lane * 8);
            // B: cells 2wid, 2wid+1 (hi then lo)
#pragma unroll
            for (int j = 0; j < 2; ++j) {
                const int c = 2 * wid + j;
                gload16(Bh + (long)(n0 + c * 16 + sr) * ldb + kb + sc,
                        bp + (2 * NCA + c) * 512 + lane * 8);
                gload16(Bl + (long)(n0 + c * 16 + sr) * ldb + kb + sc,
                        bp + (2 * NCA + NCB + c) * 512 + lane * 8);
            }
        } else {
            constexpr int APW = NCA / W, BPW = NCB / W;
#pragma unroll
            for (int i = 0; i < APW; ++i) {
                const int c = wid * APW + i;
                gload16(Ahi + (long)(m0 + c * 16 + sr) * lda + kb + sc,
                        bp + c * 512 + lane * 8);
            }
#pragma unroll
            for (int j = 0; j < BPW; ++j) {
                const int c = wid * BPW + j;
                gload16(Bh + (long)(n0 + c * 16 + sr) * ldb + kb + sc,
                        bp + (NCA + c) * 512 + lane * 8);
            }
        }
    };

    // prologue: stage tiles 0,1; drain tile 0's stages (counted)
    stage(0, smem);
    if (ksteps > 1) stage(1, smem + BUFU);
    vmf_spw<SPW>();
    BAR();

    int bufi = 0;
    for (int t = 0; t < ksteps; ++t) {
        u16* bp = smem + bufi * BUFU;
        const bool h2 = (t + 2 < ksteps);
        // issue next-next tile's DMA first (T14 issue-early; disjoint buffer)
        if (h2) {
            int nb = bufi + 2; if (nb >= 3) nb -= 3;
            stage(t + 2, smem + nb * BUFU);
        }
        if constexpr (SPLIT3) {
            bf16x8 ah[4], al[4], bh[4], bl[4];
#pragma unroll
            for (int i = 0; i < 4; ++i) {
                ah[i] = *(const bf16x8*)(bp + (wm * 4 + i) * 512 + rdo);
                al[i] = *(const bf16x8*)(bp + (NCA + wm * 4 + i) * 512 + rdo);
            }
#pragma unroll
            for (int j = 0; j < 4; ++j) {
                bh[j] = *(const bf16x8*)(bp + (2 * NCA + wn * 4 + j) * 512 + rdo);
                bl[j] = *(const bf16x8*)(bp + (2 * NCA + NCB + wn * 4 + j) * 512 + rdo);
            }
            __builtin_amdgcn_s_setprio(1);
            // variant-OUTERMOST: 16 independent MFMAs between acc reuses.
            // Per-acc order still hh -> hl -> lh (bit-identical to R13).
#pragma unroll
            for (int v = 0; v < 3; ++v) {
#pragma unroll
                for (int i = 0; i < 4; ++i)
#pragma unroll
                    for (int j = 0; j < 4; ++j) {
                        const bf16x8& va = (v == 2) ? al[i] : ah[i];
                        const bf16x8& vb = (v == 1) ? bl[j] : bh[j];
                        acc[i][j] = MFMA16(va, vb, acc[i][j]);
                    }
            }
            __builtin_amdgcn_s_setprio(0);
        } else {
            bf16x8 a[4], b[4];
#pragma unroll
            for (int i = 0; i < 4; ++i)
                a[i] = *(const bf16x8*)(bp + (wm * 4 + i) * 512 + rdo);
#pragma unroll
            for (int j = 0; j < 4; ++j)
                b[j] = *(const bf16x8*)(bp + (NCA + wn * 4 + j) * 512 + rdo);
            __builtin_amdgcn_s_setprio(1);
#pragma unroll
            for (int i = 0; i < 4; ++i)
#pragma unroll
                for (int j = 0; j < 4; ++j) acc[i][j] = MFMA16(a[i], b[j], acc[i][j]);
            __builtin_amdgcn_s_setprio(0);
        }
        // single per-iteration fence+barrier: drains stage(t+1), publishes
        if (h2) {
            vmf_spw<SPW>();
        } else if (t + 1 < ksteps) {
            VMF(0);
        }
        BAR();
        ++bufi; if (bufi == 3) bufi = 0;
    }

    // epilogue: C/D layout col=lane&15, row=(lane>>4)*4+reg (R1-verified)
    const int rlane = lane & 15;
    const int crow = m0 + wm * 64 + (lane >> 4) * 4;
    const int ccol = n0 + wn * 64 + rlane;
#pragma unroll
    for (int i = 0; i < 4; ++i) {
#pragma unroll
        for (int j = 0; j < 4; ++j) {
            const int nn = ccol + j * 16;
            if (NGUARD && nn >= Nbuf) continue;
#pragma unroll
            for (int rr = 0; rr < 4; ++rr) {
                const int mm = crow + i * 16 + rr;
                const long off = (long)mm * ldc + nn;
                float v = acc[i][j][rr];
                if (NGUARD && nn >= Nlim) v = 0.f;
                if (SPLIT_OUT) {
                    u16 hh = f2bf(v);
                    Chi[off] = hh;
                    Clo[off] = f2bf(v - bf2f(hh));
                } else {
                    C[off] = v;
                }
            }
        }
    }
}

// ---------------- host ----------------

extern "C" void kernel_launch(void* const* d_in, const int* in_sizes, int n_in,
                              void* d_out, int out_size, void* d_ws, size_t ws_size,
                              hipStream_t stream) {
    const float* h = (const float*)d_in[0];
    const float* W = (const float*)d_in[1];
    float* out = (float*)d_out;

    char* ws = (char*)d_ws;
    size_t off = 0;
    auto alloc = [&](size_t bytes) -> void* {
        void* p = ws + off;
        off += (bytes + 255) & ~(size_t)255;
        return p;
    };
    const size_t MD = (size_t)M1 * KP;
    u16* h_hi  = (u16*)alloc(MD * 2);
    u16* h_lo  = (u16*)alloc(MD * 2);
    u16* hW_hi = (u16*)alloc(MD * 2);
    u16* hW_lo = (u16*)alloc(MD * 2);
    u16* hT    = (u16*)alloc((size_t)BB * 1024 * SS * 2);
    u16* Wt_hi = (u16*)alloc((size_t)1024 * KP * 2);
    u16* Wt_lo = (u16*)alloc((size_t)1024 * KP * 2);
    float* scores = (float*)alloc((size_t)4 * SS * SS * 4);   // 4-batch chunk

    (void)hipFuncSetAttribute(reinterpret_cast<const void*>(&gemmT<256, 4, 1, 1, 1>),
                              hipFuncAttributeMaxDynamicSharedMemorySize, 147456);
    (void)hipFuncSetAttribute(reinterpret_cast<const void*>(&gemmT<256, 4, 1, 0, 0>),
                              hipFuncAttributeMaxDynamicSharedMemorySize, 147456);
    (void)hipFuncSetAttribute(reinterpret_cast<const void*>(&gemmT<128, 2, 0, 0, 1>),
                              hipFuncAttributeMaxDynamicSharedMemorySize, 49152);

    // prep
    hsplit_kernel<<<dim3(16384 * 208 / 256), dim3(256), 0, stream>>>(h, h_hi, h_lo);
    wsplit_kernel<<<dim3(1024 * KP / 256), dim3(256), 0, stream>>>(W, Wt_hi, Wt_lo);
    transpose_kernel<<<dim3(SS / 32, 32, BB), dim3(32, 8), 0, stream>>>(h_hi, hT);

    // GEMM1: hW = h @ W  (M=16384, N=1024pad, 26 K32-tiles fused), split-out
    gemmT<256, 4, 1, 1, 1><<<dim3(512), dim3(512), 147456, stream>>>(
        h_hi, h_lo, KP,
        Wt_hi, Wt_lo, 0L, KP,
        nullptr, hW_hi, hW_lo,
        KP, DD, KP, 26, 128);

    for (int b0 = 0; b0 < BB; b0 += 4) {
        const long aoff = (long)b0 * SS * KP;
        // GEMM2: scores = hW @ h^T  (chunk M=8192 m-merged, N=2048/batch, 26 K32)
        gemmT<256, 4, 1, 0, 0><<<dim3(512), dim3(512), 147456, stream>>>(
            hW_hi + aoff, hW_lo + aoff, KP,
            h_hi + aoff, h_lo + aoff, (long)SS * KP, KP,
            scores, nullptr, nullptr,
            SS, SS, SS, 26, 64);
        // softmax rows -> bf16 attn in place (pitch 4096 u16)
        softmax_kernel<<<dim3(4 * SS), dim3(256), 0, stream>>>(scores);
        // PV: out = attn @ h  (chunk M=8192, N=7x128=896>=800, K=2048)
        gemmT<128, 2, 0, 0, 1><<<dim3(448), dim3(256), 49152, stream>>>(
            (const u16*)scores, nullptr, SS * 2,
            hT + (long)b0 * 1024 * SS, nullptr, (long)1024 * SS, SS,
            out + (long)b0 * SS * DD, nullptr, nullptr,
            DD, DD, DD, 64, 64);
    }
}